// Round 1
// baseline (2200.795 us; speedup 1.0000x reference)
//
#include <hip/hip_runtime.h>
#include <cstddef>
#include <cstdint>

static inline int divup(int a, int b) { return (a + b - 1) / b; }

// deg[i] starts at 1.0 (self-loop)
__global__ void k_init_deg(float* __restrict__ deg, int n) {
    int i = blockIdx.x * blockDim.x + threadIdx.x;
    if (i < n) deg[i] = 1.0f;
}

__global__ void k_count_deg(const int* __restrict__ dst, float* __restrict__ deg, int E) {
    int e = blockIdx.x * blockDim.x + threadIdx.x;
    if (e < E) unsafeAtomicAdd(&deg[dst[e]], 1.0f);
}

__global__ void k_make_dinv(float* __restrict__ deg, int n) {
    int i = blockIdx.x * blockDim.x + threadIdx.x;
    if (i < n) deg[i] = rsqrtf(deg[i]);   // deg >= 1 always (self-loop)
}

// hs[row,col] = (x[row,:] @ W1[:,col]) * dinv[row];  acc[row,col] = same (self-loop init)
__global__ __launch_bounds__(256) void k_gemm1(const float* __restrict__ x,
                                               const float* __restrict__ W1,
                                               const float* __restrict__ dinv,
                                               float* __restrict__ hs,
                                               float* __restrict__ acc, int n) {
    __shared__ float sW[64 * 128];   // 32 KiB
    __shared__ float sx[2][64];
    for (int i = threadIdx.x; i < 64 * 128; i += 256) sW[i] = W1[i];
    const int col = threadIdx.x & 127;
    const int r2  = threadIdx.x >> 7;
    const int row0 = blockIdx.x * 2;
    if (threadIdx.x < 128) {
        int rr = threadIdx.x >> 6, cc = threadIdx.x & 63;
        int row = row0 + rr;
        if (row < n) sx[rr][cc] = x[(size_t)row * 64 + cc];
    }
    __syncthreads();
    const int row = row0 + r2;
    if (row < n) {
        float a = 0.f;
        #pragma unroll
        for (int k = 0; k < 64; ++k) a = fmaf(sx[r2][k], sW[k * 128 + col], a);
        float v = a * dinv[row];
        hs[(size_t)row * 128 + col]  = v;
        acc[(size_t)row * 128 + col] = v;
    }
}

// 32 lanes per edge, float4 gather + 4 scalar HW fadd atomics (128 cols)
__global__ __launch_bounds__(256) void k_scatter1(const int* __restrict__ src,
                                                  const int* __restrict__ dst,
                                                  const float* __restrict__ hs,
                                                  float* __restrict__ acc, int E) {
    int t = blockIdx.x * blockDim.x + threadIdx.x;
    int e = t >> 5;
    if (e >= E) return;
    int lane = t & 31;
    int s = src[e], d = dst[e];
    const float4 v = *reinterpret_cast<const float4*>(hs + (size_t)s * 128 + lane * 4);
    float* dp = acc + (size_t)d * 128 + lane * 4;
    unsafeAtomicAdd(dp + 0, v.x);
    unsafeAtomicAdd(dp + 1, v.y);
    unsafeAtomicAdd(dp + 2, v.z);
    unsafeAtomicAdd(dp + 3, v.w);
}

// h1f = relu(acc1*dinv + b1); hs2[row,col] = (h1f @ W2)[row,col] * dinv[row]; outacc = same
__global__ __launch_bounds__(256) void k_gemm2(const float* __restrict__ acc1,
                                               const float* __restrict__ b1,
                                               const float* __restrict__ W2,
                                               const float* __restrict__ dinv,
                                               float* __restrict__ hs2,
                                               float* __restrict__ outacc, int n) {
    __shared__ float sW[128 * 64];   // 32 KiB
    __shared__ float sh[4][128];
    for (int i = threadIdx.x; i < 128 * 64; i += 256) sW[i] = W2[i];
    const int row0 = blockIdx.x * 4;
    for (int i = threadIdx.x; i < 512; i += 256) {
        int rr = i >> 7, cc = i & 127;
        int row = row0 + rr;
        if (row < n) sh[rr][cc] = fmaxf(fmaf(acc1[(size_t)row * 128 + cc], dinv[row], b1[cc]), 0.f);
    }
    __syncthreads();
    const int col = threadIdx.x & 63;
    const int r4  = threadIdx.x >> 6;
    const int row = row0 + r4;
    if (row < n) {
        float a = 0.f;
        #pragma unroll
        for (int k = 0; k < 128; ++k) a = fmaf(sh[r4][k], sW[k * 64 + col], a);
        float v = a * dinv[row];
        hs2[(size_t)row * 64 + col]    = v;
        outacc[(size_t)row * 64 + col] = v;
    }
}

// 16 lanes per edge, float4 gather + 4 atomics (64 cols)
__global__ __launch_bounds__(256) void k_scatter2(const int* __restrict__ src,
                                                  const int* __restrict__ dst,
                                                  const float* __restrict__ hs,
                                                  float* __restrict__ acc, int E) {
    int t = blockIdx.x * blockDim.x + threadIdx.x;
    int e = t >> 4;
    if (e >= E) return;
    int lane = t & 15;
    int s = src[e], d = dst[e];
    const float4 v = *reinterpret_cast<const float4*>(hs + (size_t)s * 64 + lane * 4);
    float* dp = acc + (size_t)d * 64 + lane * 4;
    unsafeAtomicAdd(dp + 0, v.x);
    unsafeAtomicAdd(dp + 1, v.y);
    unsafeAtomicAdd(dp + 2, v.z);
    unsafeAtomicAdd(dp + 3, v.w);
}

// out = relu(out*dinv[row] + b2[col]) in place
__global__ void k_finish(float* __restrict__ out, const float* __restrict__ dinv,
                         const float* __restrict__ b2, int total) {
    int i = blockIdx.x * blockDim.x + threadIdx.x;
    if (i < total) {
        int row = i >> 6, c = i & 63;
        out[i] = fmaxf(fmaf(out[i], dinv[row], b2[c]), 0.f);
    }
}

extern "C" void kernel_launch(void* const* d_in, const int* in_sizes, int n_in,
                              void* d_out, int out_size, void* d_ws, size_t ws_size,
                              hipStream_t stream) {
    const float* x  = (const float*)d_in[0];
    const int*   ei = (const int*)d_in[1];     // int32 on device (JAX x64 disabled)
    const float* W1 = (const float*)d_in[2];
    const float* b1 = (const float*)d_in[3];
    const float* W2 = (const float*)d_in[4];
    const float* b2 = (const float*)d_in[5];
    float* out = (float*)d_out;

    const int n = in_sizes[0] / 64;     // 50000
    const int E = in_sizes[1] / 2;      // 800000
    const int* src = ei;                // edge_index[0]
    const int* dst = ei + E;            // edge_index[1]

    char* ws = (char*)d_ws;
    float* dinv = (float*)ws;
    size_t off = ((size_t)n * 4 + 255) & ~(size_t)255;
    float* hs1  = (float*)(ws + off); off += (size_t)n * 128 * 4;
    float* acc1 = (float*)(ws + off);
    float* hs2  = hs1;                  // hs1 dead after scatter1 — reuse

    k_init_deg <<<divup(n, 256), 256, 0, stream>>>(dinv, n);
    k_count_deg<<<divup(E, 256), 256, 0, stream>>>(dst, dinv, E);
    k_make_dinv<<<divup(n, 256), 256, 0, stream>>>(dinv, n);

    k_gemm1<<<divup(n, 2), 256, 0, stream>>>(x, W1, dinv, hs1, acc1, n);
    k_scatter1<<<divup(E * 32, 256), 256, 0, stream>>>(src, dst, hs1, acc1, E);

    k_gemm2<<<divup(n, 4), 256, 0, stream>>>(acc1, b1, W2, dinv, hs2, out, n);
    k_scatter2<<<divup(E * 16, 256), 256, 0, stream>>>(src, dst, hs2, out, E);

    k_finish<<<divup(n * 64, 256), 256, 0, stream>>>(out, dinv, b2, n * 64);
}

// Round 2
// 495.201 us; speedup vs baseline: 4.4442x; 4.4442x over previous
//
#include <hip/hip_runtime.h>
#include <cstddef>
#include <cstdint>

static inline int divup(int a, int b) { return (a + b - 1) / b; }

__global__ void k_zero(int* __restrict__ p, int n) {
    int i = blockIdx.x * blockDim.x + threadIdx.x;
    if (i < n) p[i] = 0;
}

__global__ void k_count(const int* __restrict__ dst, int* __restrict__ cnt, int E) {
    int e = blockIdx.x * blockDim.x + threadIdx.x;
    if (e < E) atomicAdd(&cnt[dst[e]], 1);
}

// Single-block exclusive scan over cnt[n] -> rowptr/cursor; dinv = rsqrt(cnt+1).
__global__ __launch_bounds__(1024) void k_scan(const int* __restrict__ cnt,
                                               int* __restrict__ rowptr,
                                               int* __restrict__ cursor,
                                               float* __restrict__ dinv, int n) {
    __shared__ int part[1024];
    const int t = threadIdx.x;
    const int chunk = (n + 1023) >> 10;           // 49 for n=50000
    const int i0 = t * chunk;
    const int i1 = min(n, i0 + chunk);
    int s = 0;
    for (int i = i0; i < i1; ++i) s += cnt[i];
    part[t] = s;
    __syncthreads();
    for (int d = 1; d < 1024; d <<= 1) {          // Hillis-Steele inclusive scan
        int v = (t >= d) ? part[t - d] : 0;
        __syncthreads();
        part[t] += v;
        __syncthreads();
    }
    int run = (t == 0) ? 0 : part[t - 1];         // exclusive base for this chunk
    for (int i = i0; i < i1; ++i) {
        int c = cnt[i];
        rowptr[i] = run;
        cursor[i] = run;
        dinv[i] = rsqrtf((float)(c + 1));         // +1 self-loop
        run += c;
    }
    if (t == 1023) rowptr[n] = part[1023];        // = E
}

__global__ void k_fill(const int* __restrict__ src, const int* __restrict__ dst,
                       int* __restrict__ cursor, int* __restrict__ eidx, int E) {
    int e = blockIdx.x * blockDim.x + threadIdx.x;
    if (e < E) {
        int d = dst[e];
        int pos = atomicAdd(&cursor[d], 1);
        eidx[pos] = src[e];
    }
}

// hs1[row,col] = (x[row,:] @ W1[:,col]) * dinv[row]   (8 rows/block)
__global__ __launch_bounds__(256) void k_gemm1(const float* __restrict__ x,
                                               const float* __restrict__ W1,
                                               const float* __restrict__ dinv,
                                               float* __restrict__ hs, int n) {
    __shared__ float sW[64 * 128];   // 32 KiB
    __shared__ float sx[8][64];
    const int t = threadIdx.x;
    for (int i = t; i < 64 * 128; i += 256) sW[i] = W1[i];
    const int row0 = blockIdx.x * 8;
    for (int i = t; i < 512; i += 256) {
        int rr = i >> 6, cc = i & 63;
        int row = row0 + rr;
        sx[rr][cc] = (row < n) ? x[(size_t)row * 64 + cc] : 0.f;
    }
    __syncthreads();
    const int col = t & 127;
    const int rh  = t >> 7;                        // wave-uniform
    float a0 = 0.f, a1 = 0.f, a2 = 0.f, a3 = 0.f;
    #pragma unroll
    for (int k = 0; k < 64; ++k) {
        float w = sW[k * 128 + col];
        a0 = fmaf(sx[rh + 0][k], w, a0);
        a1 = fmaf(sx[rh + 2][k], w, a1);
        a2 = fmaf(sx[rh + 4][k], w, a2);
        a3 = fmaf(sx[rh + 6][k], w, a3);
    }
    float r[4] = {a0, a1, a2, a3};
    #pragma unroll
    for (int j = 0; j < 4; ++j) {
        int row = row0 + rh + 2 * j;
        if (row < n) hs[(size_t)row * 128 + col] = r[j] * dinv[row];
    }
}

// h1f[i,:] = relu((hs1[i,:] + sum_{s in N_in(i)} hs1[s,:]) * dinv[i] + b1)
__global__ __launch_bounds__(256) void k_agg1(const int* __restrict__ rowptr,
                                              const int* __restrict__ eidx,
                                              const float* __restrict__ hs,
                                              const float* __restrict__ dinv,
                                              const float* __restrict__ b1,
                                              float* __restrict__ h1f, int n) {
    int t = blockIdx.x * blockDim.x + threadIdx.x;
    int node = t >> 5;
    if (node >= n) return;
    int lane = t & 31;
    const size_t co = (size_t)lane * 4;
    int b = rowptr[node], eN = rowptr[node + 1];
    float4 a = *reinterpret_cast<const float4*>(hs + (size_t)node * 128 + co);
    for (int e = b; e < eN; ++e) {
        int s = eidx[e];
        const float4 v = *reinterpret_cast<const float4*>(hs + (size_t)s * 128 + co);
        a.x += v.x; a.y += v.y; a.z += v.z; a.w += v.w;
    }
    float di = dinv[node];
    const float4 bb = *reinterpret_cast<const float4*>(b1 + co);
    float4 o;
    o.x = fmaxf(fmaf(a.x, di, bb.x), 0.f);
    o.y = fmaxf(fmaf(a.y, di, bb.y), 0.f);
    o.z = fmaxf(fmaf(a.z, di, bb.z), 0.f);
    o.w = fmaxf(fmaf(a.w, di, bb.w), 0.f);
    *reinterpret_cast<float4*>(h1f + (size_t)node * 128 + co) = o;
}

// hs2[row,col] = (h1f[row,:] @ W2[:,col]) * dinv[row]   (8 rows/block)
__global__ __launch_bounds__(256) void k_gemm2(const float* __restrict__ h1f,
                                               const float* __restrict__ W2,
                                               const float* __restrict__ dinv,
                                               float* __restrict__ hs2, int n) {
    __shared__ float sW[128 * 64];   // 32 KiB
    __shared__ float sh[8][128];
    const int t = threadIdx.x;
    for (int i = t; i < 128 * 64; i += 256) sW[i] = W2[i];
    const int row0 = blockIdx.x * 8;
    for (int i = t; i < 1024; i += 256) {
        int rr = i >> 7, cc = i & 127;
        int row = row0 + rr;
        sh[rr][cc] = (row < n) ? h1f[(size_t)row * 128 + cc] : 0.f;
    }
    __syncthreads();
    const int col = t & 63;
    const int rq  = t >> 6;                        // 0..3, wave-uniform
    float a0 = 0.f, a1 = 0.f;
    #pragma unroll
    for (int k = 0; k < 128; ++k) {
        float w = sW[k * 64 + col];
        a0 = fmaf(sh[rq][k], w, a0);
        a1 = fmaf(sh[rq + 4][k], w, a1);
    }
    int r0 = row0 + rq, r1 = row0 + rq + 4;
    if (r0 < n) hs2[(size_t)r0 * 64 + col] = a0 * dinv[r0];
    if (r1 < n) hs2[(size_t)r1 * 64 + col] = a1 * dinv[r1];
}

// out[i,:] = relu((hs2[i,:] + sum_{s in N_in(i)} hs2[s,:]) * dinv[i] + b2)
__global__ __launch_bounds__(256) void k_agg2(const int* __restrict__ rowptr,
                                              const int* __restrict__ eidx,
                                              const float* __restrict__ hs,
                                              const float* __restrict__ dinv,
                                              const float* __restrict__ b2,
                                              float* __restrict__ out, int n) {
    int t = blockIdx.x * blockDim.x + threadIdx.x;
    int node = t >> 4;
    if (node >= n) return;
    int lane = t & 15;
    const size_t co = (size_t)lane * 4;
    int b = rowptr[node], eN = rowptr[node + 1];
    float4 a = *reinterpret_cast<const float4*>(hs + (size_t)node * 64 + co);
    for (int e = b; e < eN; ++e) {
        int s = eidx[e];
        const float4 v = *reinterpret_cast<const float4*>(hs + (size_t)s * 64 + co);
        a.x += v.x; a.y += v.y; a.z += v.z; a.w += v.w;
    }
    float di = dinv[node];
    const float4 bb = *reinterpret_cast<const float4*>(b2 + co);
    float4 o;
    o.x = fmaxf(fmaf(a.x, di, bb.x), 0.f);
    o.y = fmaxf(fmaf(a.y, di, bb.y), 0.f);
    o.z = fmaxf(fmaf(a.z, di, bb.z), 0.f);
    o.w = fmaxf(fmaf(a.w, di, bb.w), 0.f);
    *reinterpret_cast<float4*>(out + (size_t)node * 64 + co) = o;
}

extern "C" void kernel_launch(void* const* d_in, const int* in_sizes, int n_in,
                              void* d_out, int out_size, void* d_ws, size_t ws_size,
                              hipStream_t stream) {
    const float* x  = (const float*)d_in[0];
    const int*   ei = (const int*)d_in[1];
    const float* W1 = (const float*)d_in[2];
    const float* b1 = (const float*)d_in[3];
    const float* W2 = (const float*)d_in[4];
    const float* b2 = (const float*)d_in[5];
    float* out = (float*)d_out;

    const int n = in_sizes[0] / 64;     // 50000
    const int E = in_sizes[1] / 2;      // 800000
    const int* src = ei;
    const int* dst = ei + E;

    char* ws = (char*)d_ws;
    size_t off = 0;
    auto alloc = [&](size_t bytes) { void* p = ws + off; off = (off + bytes + 255) & ~(size_t)255; return p; };
    int*   cnt    = (int*)  alloc((size_t)n * 4);
    int*   rowptr = (int*)  alloc((size_t)(n + 1) * 4);
    int*   cursor = (int*)  alloc((size_t)n * 4);
    float* dinv   = (float*)alloc((size_t)n * 4);
    int*   eidx   = (int*)  alloc((size_t)E * 4);
    float* hs1    = (float*)alloc((size_t)n * 128 * 4);
    float* h1f    = (float*)alloc((size_t)n * 128 * 4);
    float* hs2    = hs1;     // hs1 dead after k_agg1; reuse for layer-2 staging

    // CSR build
    k_zero <<<divup(n, 256), 256, 0, stream>>>(cnt, n);
    k_count<<<divup(E, 256), 256, 0, stream>>>(dst, cnt, E);
    k_scan <<<1, 1024, 0, stream>>>(cnt, rowptr, cursor, dinv, n);
    k_fill <<<divup(E, 256), 256, 0, stream>>>(src, dst, cursor, eidx, E);

    // layer 1
    k_gemm1<<<divup(n, 8), 256, 0, stream>>>(x, W1, dinv, hs1, n);
    k_agg1 <<<divup(n * 32, 256), 256, 0, stream>>>(rowptr, eidx, hs1, dinv, b1, h1f, n);

    // layer 2
    k_gemm2<<<divup(n, 8), 256, 0, stream>>>(h1f, W2, dinv, hs2, n);
    k_agg2 <<<divup(n * 16, 256), 256, 0, stream>>>(rowptr, eidx, hs2, dinv, b2, out, n);
}

// Round 3
// 376.152 us; speedup vs baseline: 5.8508x; 1.3165x over previous
//
#include <hip/hip_runtime.h>
#include <cstddef>
#include <cstdint>

static inline int divup(int a, int b) { return (a + b - 1) / b; }

// 4 edges/thread histogram of dst
__global__ void k_count(const int* __restrict__ dst, int* __restrict__ cnt, int E) {
    int i = blockIdx.x * blockDim.x + threadIdx.x;
    int base = i * 4;
    if (base + 3 < E) {
        int4 d = *reinterpret_cast<const int4*>(dst + base);
        atomicAdd(&cnt[d.x], 1); atomicAdd(&cnt[d.y], 1);
        atomicAdd(&cnt[d.z], 1); atomicAdd(&cnt[d.w], 1);
    } else if (base < E) {
        for (int j = base; j < E; ++j) atomicAdd(&cnt[dst[j]], 1);
    }
}

// block-chunk sums of cnt
__global__ __launch_bounds__(256) void k_s1(const int* __restrict__ cnt, int* __restrict__ bsum, int n) {
    __shared__ int part[256];
    int t = threadIdx.x;
    int i = blockIdx.x * 256 + t;
    part[t] = (i < n) ? cnt[i] : 0;
    __syncthreads();
    for (int d = 128; d > 0; d >>= 1) {
        if (t < d) part[t] += part[t + d];
        __syncthreads();
    }
    if (t == 0) bsum[blockIdx.x] = part[0];
}

// scan block sums (G <= 256), write rowptr[n] = E
__global__ __launch_bounds__(256) void k_s2(const int* __restrict__ bsum, int* __restrict__ bbase,
                                            int* __restrict__ rowptr, int G, int n) {
    __shared__ int part[256];
    int t = threadIdx.x;
    int v = (t < G) ? bsum[t] : 0;
    part[t] = v;
    __syncthreads();
    for (int d = 1; d < 256; d <<= 1) {
        int u = (t >= d) ? part[t - d] : 0;
        __syncthreads();
        part[t] += u;
        __syncthreads();
    }
    if (t < G) bbase[t] = part[t] - v;        // exclusive base per block
    if (t == 255) rowptr[n] = part[255];      // total = E
}

// per-block scan + base; fused cursor init + dinv
__global__ __launch_bounds__(256) void k_s3(const int* __restrict__ cnt, const int* __restrict__ bbase,
                                            int* __restrict__ rowptr, int* __restrict__ cursor,
                                            float* __restrict__ dinv, int n) {
    __shared__ int part[256];
    int t = threadIdx.x;
    int i = blockIdx.x * 256 + t;
    int c = (i < n) ? cnt[i] : 0;
    part[t] = c;
    __syncthreads();
    for (int d = 1; d < 256; d <<= 1) {
        int u = (t >= d) ? part[t - d] : 0;
        __syncthreads();
        part[t] += u;
        __syncthreads();
    }
    if (i < n) {
        int excl = part[t] - c + bbase[blockIdx.x];
        rowptr[i] = excl;
        cursor[i] = excl;
        dinv[i] = rsqrtf((float)(c + 1));     // +1 self-loop
    }
}

// 4 edges/thread CSR fill via atomic cursors
__global__ void k_fill(const int* __restrict__ src, const int* __restrict__ dst,
                       int* __restrict__ cursor, int* __restrict__ eidx, int E) {
    int i = blockIdx.x * blockDim.x + threadIdx.x;
    int base = i * 4;
    if (base + 3 < E) {
        int4 d = *reinterpret_cast<const int4*>(dst + base);
        int4 s = *reinterpret_cast<const int4*>(src + base);
        eidx[atomicAdd(&cursor[d.x], 1)] = s.x;
        eidx[atomicAdd(&cursor[d.y], 1)] = s.y;
        eidx[atomicAdd(&cursor[d.z], 1)] = s.z;
        eidx[atomicAdd(&cursor[d.w], 1)] = s.w;
    } else if (base < E) {
        for (int j = base; j < E; ++j)
            eidx[atomicAdd(&cursor[dst[j]], 1)] = src[j];
    }
}

// hs1[row,col] = (x[row,:] @ W1[:,col]) * dinv[row]   (8 rows/block)
__global__ __launch_bounds__(256) void k_gemm1(const float* __restrict__ x,
                                               const float* __restrict__ W1,
                                               const float* __restrict__ dinv,
                                               float* __restrict__ hs, int n) {
    __shared__ float sW[64 * 128];   // 32 KiB
    __shared__ float sx[8][64];
    const int t = threadIdx.x;
    for (int i = t; i < 64 * 128; i += 256) sW[i] = W1[i];
    const int row0 = blockIdx.x * 8;
    for (int i = t; i < 512; i += 256) {
        int rr = i >> 6, cc = i & 63;
        int row = row0 + rr;
        sx[rr][cc] = (row < n) ? x[(size_t)row * 64 + cc] : 0.f;
    }
    __syncthreads();
    const int col = t & 127;
    const int rh  = t >> 7;
    float a0 = 0.f, a1 = 0.f, a2 = 0.f, a3 = 0.f;
    #pragma unroll
    for (int k = 0; k < 64; ++k) {
        float w = sW[k * 128 + col];
        a0 = fmaf(sx[rh + 0][k], w, a0);
        a1 = fmaf(sx[rh + 2][k], w, a1);
        a2 = fmaf(sx[rh + 4][k], w, a2);
        a3 = fmaf(sx[rh + 6][k], w, a3);
    }
    float r[4] = {a0, a1, a2, a3};
    #pragma unroll
    for (int j = 0; j < 4; ++j) {
        int row = row0 + rh + 2 * j;
        if (row < n) hs[(size_t)row * 128 + col] = r[j] * dinv[row];
    }
}

// h1f[i,:] = relu((hs1[i,:] + sum_{s in N_in(i)} hs1[s,:]) * dinv[i] + b1)
__global__ __launch_bounds__(256) void k_agg1(const int* __restrict__ rowptr,
                                              const int* __restrict__ eidx,
                                              const float* __restrict__ hs,
                                              const float* __restrict__ dinv,
                                              const float* __restrict__ b1,
                                              float* __restrict__ h1f, int n) {
    int t = blockIdx.x * blockDim.x + threadIdx.x;
    int node = t >> 5;
    if (node >= n) return;
    int lane = t & 31;
    const size_t co = (size_t)lane * 4;
    int b = rowptr[node], eN = rowptr[node + 1];
    float4 a = *reinterpret_cast<const float4*>(hs + (size_t)node * 128 + co);
    for (int e = b; e < eN; ++e) {
        int s = eidx[e];
        const float4 v = *reinterpret_cast<const float4*>(hs + (size_t)s * 128 + co);
        a.x += v.x; a.y += v.y; a.z += v.z; a.w += v.w;
    }
    float di = dinv[node];
    const float4 bb = *reinterpret_cast<const float4*>(b1 + co);
    float4 o;
    o.x = fmaxf(fmaf(a.x, di, bb.x), 0.f);
    o.y = fmaxf(fmaf(a.y, di, bb.y), 0.f);
    o.z = fmaxf(fmaf(a.z, di, bb.z), 0.f);
    o.w = fmaxf(fmaf(a.w, di, bb.w), 0.f);
    *reinterpret_cast<float4*>(h1f + (size_t)node * 128 + co) = o;
}

// hs2[row,col] = (h1f[row,:] @ W2[:,col]) * dinv[row]   (8 rows/block)
__global__ __launch_bounds__(256) void k_gemm2(const float* __restrict__ h1f,
                                               const float* __restrict__ W2,
                                               const float* __restrict__ dinv,
                                               float* __restrict__ hs2, int n) {
    __shared__ float sW[128 * 64];   // 32 KiB
    __shared__ float sh[8][128];
    const int t = threadIdx.x;
    for (int i = t; i < 128 * 64; i += 256) sW[i] = W2[i];
    const int row0 = blockIdx.x * 8;
    for (int i = t; i < 1024; i += 256) {
        int rr = i >> 7, cc = i & 127;
        int row = row0 + rr;
        sh[rr][cc] = (row < n) ? h1f[(size_t)row * 128 + cc] : 0.f;
    }
    __syncthreads();
    const int col = t & 63;
    const int rq  = t >> 6;
    float a0 = 0.f, a1 = 0.f;
    #pragma unroll
    for (int k = 0; k < 128; ++k) {
        float w = sW[k * 64 + col];
        a0 = fmaf(sh[rq][k], w, a0);
        a1 = fmaf(sh[rq + 4][k], w, a1);
    }
    int r0 = row0 + rq, r1 = row0 + rq + 4;
    if (r0 < n) hs2[(size_t)r0 * 64 + col] = a0 * dinv[r0];
    if (r1 < n) hs2[(size_t)r1 * 64 + col] = a1 * dinv[r1];
}

// out[i,:] = relu((hs2[i,:] + sum_{s in N_in(i)} hs2[s,:]) * dinv[i] + b2)
__global__ __launch_bounds__(256) void k_agg2(const int* __restrict__ rowptr,
                                              const int* __restrict__ eidx,
                                              const float* __restrict__ hs,
                                              const float* __restrict__ dinv,
                                              const float* __restrict__ b2,
                                              float* __restrict__ out, int n) {
    int t = blockIdx.x * blockDim.x + threadIdx.x;
    int node = t >> 4;
    if (node >= n) return;
    int lane = t & 15;
    const size_t co = (size_t)lane * 4;
    int b = rowptr[node], eN = rowptr[node + 1];
    float4 a = *reinterpret_cast<const float4*>(hs + (size_t)node * 64 + co);
    for (int e = b; e < eN; ++e) {
        int s = eidx[e];
        const float4 v = *reinterpret_cast<const float4*>(hs + (size_t)s * 64 + co);
        a.x += v.x; a.y += v.y; a.z += v.z; a.w += v.w;
    }
    float di = dinv[node];
    const float4 bb = *reinterpret_cast<const float4*>(b2 + co);
    float4 o;
    o.x = fmaxf(fmaf(a.x, di, bb.x), 0.f);
    o.y = fmaxf(fmaf(a.y, di, bb.y), 0.f);
    o.z = fmaxf(fmaf(a.z, di, bb.z), 0.f);
    o.w = fmaxf(fmaf(a.w, di, bb.w), 0.f);
    *reinterpret_cast<float4*>(out + (size_t)node * 64 + co) = o;
}

extern "C" void kernel_launch(void* const* d_in, const int* in_sizes, int n_in,
                              void* d_out, int out_size, void* d_ws, size_t ws_size,
                              hipStream_t stream) {
    const float* x  = (const float*)d_in[0];
    const int*   ei = (const int*)d_in[1];
    const float* W1 = (const float*)d_in[2];
    const float* b1 = (const float*)d_in[3];
    const float* W2 = (const float*)d_in[4];
    const float* b2 = (const float*)d_in[5];
    float* out = (float*)d_out;

    const int n = in_sizes[0] / 64;     // 50000
    const int E = in_sizes[1] / 2;      // 800000
    const int* src = ei;
    const int* dst = ei + E;

    char* ws = (char*)d_ws;
    size_t off = 0;
    auto alloc = [&](size_t bytes) { void* p = ws + off; off = (off + bytes + 255) & ~(size_t)255; return p; };
    const int G = divup(n, 256);        // 196 scan blocks
    int*   cnt    = (int*)  alloc((size_t)n * 4);
    int*   rowptr = (int*)  alloc((size_t)(n + 1) * 4);
    int*   cursor = (int*)  alloc((size_t)n * 4);
    float* dinv   = (float*)alloc((size_t)n * 4);
    int*   bsum   = (int*)  alloc((size_t)G * 4);
    int*   bbase  = (int*)  alloc((size_t)G * 4);
    int*   eidx   = (int*)  alloc((size_t)E * 4);
    float* hs1    = (float*)alloc((size_t)n * 128 * 4);
    float* h1f    = (float*)alloc((size_t)n * 128 * 4);
    float* hs2    = hs1;     // hs1 dead after k_agg1; reuse

    // CSR build
    hipMemsetAsync(cnt, 0, (size_t)n * 4, stream);
    k_count<<<divup(divup(E, 4), 256), 256, 0, stream>>>(dst, cnt, E);
    k_s1 <<<G, 256, 0, stream>>>(cnt, bsum, n);
    k_s2 <<<1, 256, 0, stream>>>(bsum, bbase, rowptr, G, n);
    k_s3 <<<G, 256, 0, stream>>>(cnt, bbase, rowptr, cursor, dinv, n);
    k_fill<<<divup(divup(E, 4), 256), 256, 0, stream>>>(src, dst, cursor, eidx, E);

    // layer 1
    k_gemm1<<<divup(n, 8), 256, 0, stream>>>(x, W1, dinv, hs1, n);
    k_agg1 <<<divup(n * 32, 256), 256, 0, stream>>>(rowptr, eidx, hs1, dinv, b1, h1f, n);

    // layer 2
    k_gemm2<<<divup(n, 8), 256, 0, stream>>>(h1f, W2, dinv, hs2, n);
    k_agg2 <<<divup(n * 16, 256), 256, 0, stream>>>(rowptr, eidx, hs2, dinv, b2, out, n);
}

// Round 4
// 231.062 us; speedup vs baseline: 9.5247x; 1.6279x over previous
//
#include <hip/hip_runtime.h>
#include <cstddef>
#include <cstdint>

static inline int divup(int a, int b) { return (a + b - 1) / b; }

// 4 edges/thread histogram of dst
__global__ void k_count(const int* __restrict__ dst, int* __restrict__ cnt, int E) {
    int i = blockIdx.x * blockDim.x + threadIdx.x;
    int base = i * 4;
    if (base + 3 < E) {
        int4 d = *reinterpret_cast<const int4*>(dst + base);
        atomicAdd(&cnt[d.x], 1); atomicAdd(&cnt[d.y], 1);
        atomicAdd(&cnt[d.z], 1); atomicAdd(&cnt[d.w], 1);
    } else if (base < E) {
        for (int j = base; j < E; ++j) atomicAdd(&cnt[dst[j]], 1);
    }
}

__global__ __launch_bounds__(256) void k_s1(const int* __restrict__ cnt, int* __restrict__ bsum, int n) {
    __shared__ int part[256];
    int t = threadIdx.x;
    int i = blockIdx.x * 256 + t;
    part[t] = (i < n) ? cnt[i] : 0;
    __syncthreads();
    for (int d = 128; d > 0; d >>= 1) {
        if (t < d) part[t] += part[t + d];
        __syncthreads();
    }
    if (t == 0) bsum[blockIdx.x] = part[0];
}

__global__ __launch_bounds__(256) void k_s2(const int* __restrict__ bsum, int* __restrict__ bbase,
                                            int* __restrict__ rowptr, int G, int n) {
    __shared__ int part[256];
    int t = threadIdx.x;
    int v = (t < G) ? bsum[t] : 0;
    part[t] = v;
    __syncthreads();
    for (int d = 1; d < 256; d <<= 1) {
        int u = (t >= d) ? part[t - d] : 0;
        __syncthreads();
        part[t] += u;
        __syncthreads();
    }
    if (t < G) bbase[t] = part[t] - v;
    if (t == 255) rowptr[n] = part[255];
}

__global__ __launch_bounds__(256) void k_s3(const int* __restrict__ cnt, const int* __restrict__ bbase,
                                            int* __restrict__ rowptr, int* __restrict__ cursor,
                                            float* __restrict__ dinv, int n) {
    __shared__ int part[256];
    int t = threadIdx.x;
    int i = blockIdx.x * 256 + t;
    int c = (i < n) ? cnt[i] : 0;
    part[t] = c;
    __syncthreads();
    for (int d = 1; d < 256; d <<= 1) {
        int u = (t >= d) ? part[t - d] : 0;
        __syncthreads();
        part[t] += u;
        __syncthreads();
    }
    if (i < n) {
        int excl = part[t] - c + bbase[blockIdx.x];
        rowptr[i] = excl;
        cursor[i] = excl;
        dinv[i] = rsqrtf((float)(c + 1));
    }
}

__global__ void k_fill(const int* __restrict__ src, const int* __restrict__ dst,
                       int* __restrict__ cursor, int* __restrict__ eidx, int E) {
    int i = blockIdx.x * blockDim.x + threadIdx.x;
    int base = i * 4;
    if (base + 3 < E) {
        int4 d = *reinterpret_cast<const int4*>(dst + base);
        int4 s = *reinterpret_cast<const int4*>(src + base);
        eidx[atomicAdd(&cursor[d.x], 1)] = s.x;
        eidx[atomicAdd(&cursor[d.y], 1)] = s.y;
        eidx[atomicAdd(&cursor[d.z], 1)] = s.z;
        eidx[atomicAdd(&cursor[d.w], 1)] = s.w;
    } else if (base < E) {
        for (int j = base; j < E; ++j)
            eidx[atomicAdd(&cursor[dst[j]], 1)] = src[j];
    }
}

// register-tiled GEMM1: hs[row,col] = (x @ W1)[row,col] * dinv[row]
// 64-row tile, 256 threads, thread = 4 rows x (4+4) cols; A staged k-major.
__global__ __launch_bounds__(256) void k_gemm1(const float* __restrict__ x,
                                               const float* __restrict__ W1,
                                               const float* __restrict__ dinv,
                                               float* __restrict__ hs, int n) {
    __shared__ float sA[64][64];     // [k][row]  16 KiB
    __shared__ float sW[64][128];    // [k][col]  32 KiB
    const int t = threadIdx.x;
    const int r0 = blockIdx.x * 64;
    for (int i = t; i < 64 * 32; i += 256) {               // W1: 2048 float4
        int k = i >> 5, c4 = (i & 31) * 4;
        *reinterpret_cast<float4*>(&sW[k][c4]) = *reinterpret_cast<const float4*>(W1 + k * 128 + c4);
    }
    for (int i = t; i < 64 * 16; i += 256) {               // A: 1024 float4, transpose
        int row = i & 63, kq = i >> 6;
        int gr = r0 + row;
        float4 v = {0.f, 0.f, 0.f, 0.f};
        if (gr < n) v = *reinterpret_cast<const float4*>(x + (size_t)gr * 64 + kq * 4);
        sA[kq * 4 + 0][row] = v.x; sA[kq * 4 + 1][row] = v.y;
        sA[kq * 4 + 2][row] = v.z; sA[kq * 4 + 3][row] = v.w;
    }
    __syncthreads();
    const int tx = t & 15, ty = t >> 4;
    float acc[4][8] = {};
    #pragma unroll 8
    for (int k = 0; k < 64; ++k) {
        float4 a4 = *reinterpret_cast<const float4*>(&sA[k][ty * 4]);
        float4 w0 = *reinterpret_cast<const float4*>(&sW[k][tx * 4]);
        float4 w1 = *reinterpret_cast<const float4*>(&sW[k][64 + tx * 4]);
        float av[4] = {a4.x, a4.y, a4.z, a4.w};
        float wv[8] = {w0.x, w0.y, w0.z, w0.w, w1.x, w1.y, w1.z, w1.w};
        #pragma unroll
        for (int r = 0; r < 4; ++r)
            #pragma unroll
            for (int c = 0; c < 8; ++c)
                acc[r][c] = fmaf(av[r], wv[c], acc[r][c]);
    }
    #pragma unroll
    for (int r = 0; r < 4; ++r) {
        int row = r0 + ty * 4 + r;
        if (row < n) {
            float di = dinv[row];
            float4 o0 = {acc[r][0] * di, acc[r][1] * di, acc[r][2] * di, acc[r][3] * di};
            float4 o1 = {acc[r][4] * di, acc[r][5] * di, acc[r][6] * di, acc[r][7] * di};
            *reinterpret_cast<float4*>(hs + (size_t)row * 128 + tx * 4)      = o0;
            *reinterpret_cast<float4*>(hs + (size_t)row * 128 + 64 + tx * 4) = o1;
        }
    }
}

// h1f[i,:] = relu((hs1[i,:] + sum_{s in N_in(i)} hs1[s,:]) * dinv[i] + b1), 32 lanes/node
__global__ __launch_bounds__(256) void k_agg1(const int* __restrict__ rowptr,
                                              const int* __restrict__ eidx,
                                              const float* __restrict__ hs,
                                              const float* __restrict__ dinv,
                                              const float* __restrict__ b1,
                                              float* __restrict__ h1f, int n) {
    int t = blockIdx.x * blockDim.x + threadIdx.x;
    int node = t >> 5;
    if (node >= n) return;
    int lane = t & 31;
    const size_t co = (size_t)lane * 4;
    int b = rowptr[node], eN = rowptr[node + 1];
    float4 a = *reinterpret_cast<const float4*>(hs + (size_t)node * 128 + co);
    int e = b;
    for (; e + 4 <= eN; e += 4) {
        int s0 = eidx[e], s1 = eidx[e + 1], s2 = eidx[e + 2], s3 = eidx[e + 3];
        float4 v0 = *reinterpret_cast<const float4*>(hs + (size_t)s0 * 128 + co);
        float4 v1 = *reinterpret_cast<const float4*>(hs + (size_t)s1 * 128 + co);
        float4 v2 = *reinterpret_cast<const float4*>(hs + (size_t)s2 * 128 + co);
        float4 v3 = *reinterpret_cast<const float4*>(hs + (size_t)s3 * 128 + co);
        a.x += (v0.x + v1.x) + (v2.x + v3.x);
        a.y += (v0.y + v1.y) + (v2.y + v3.y);
        a.z += (v0.z + v1.z) + (v2.z + v3.z);
        a.w += (v0.w + v1.w) + (v2.w + v3.w);
    }
    for (; e < eN; ++e) {
        int s = eidx[e];
        float4 v = *reinterpret_cast<const float4*>(hs + (size_t)s * 128 + co);
        a.x += v.x; a.y += v.y; a.z += v.z; a.w += v.w;
    }
    float di = dinv[node];
    const float4 bb = *reinterpret_cast<const float4*>(b1 + co);
    float4 o;
    o.x = fmaxf(fmaf(a.x, di, bb.x), 0.f);
    o.y = fmaxf(fmaf(a.y, di, bb.y), 0.f);
    o.z = fmaxf(fmaf(a.z, di, bb.z), 0.f);
    o.w = fmaxf(fmaf(a.w, di, bb.w), 0.f);
    *reinterpret_cast<float4*>(h1f + (size_t)node * 128 + co) = o;
}

// register-tiled GEMM2: hs2[row,col] = (h1f @ W2)[row,col] * dinv[row]
// 64-row tile, 256 threads, thread = 4 rows x 4 cols; A staged k-major, K=128.
__global__ __launch_bounds__(256) void k_gemm2(const float* __restrict__ h1f,
                                               const float* __restrict__ W2,
                                               const float* __restrict__ dinv,
                                               float* __restrict__ hs2, int n) {
    __shared__ float sA[128][64];    // [k][row]  32 KiB
    __shared__ float sW[128][64];    // [k][col]  32 KiB
    const int t = threadIdx.x;
    const int r0 = blockIdx.x * 64;
    for (int i = t; i < 128 * 16; i += 256) {              // W2: 2048 float4
        int k = i >> 4, c4 = (i & 15) * 4;
        *reinterpret_cast<float4*>(&sW[k][c4]) = *reinterpret_cast<const float4*>(W2 + k * 64 + c4);
    }
    for (int i = t; i < 64 * 32; i += 256) {               // A: 2048 float4, transpose
        int row = i & 63, kq = i >> 6;                     // kq 0..31
        int gr = r0 + row;
        float4 v = {0.f, 0.f, 0.f, 0.f};
        if (gr < n) v = *reinterpret_cast<const float4*>(h1f + (size_t)gr * 128 + kq * 4);
        sA[kq * 4 + 0][row] = v.x; sA[kq * 4 + 1][row] = v.y;
        sA[kq * 4 + 2][row] = v.z; sA[kq * 4 + 3][row] = v.w;
    }
    __syncthreads();
    const int tx = t & 15, ty = t >> 4;
    float acc[4][4] = {};
    #pragma unroll 8
    for (int k = 0; k < 128; ++k) {
        float4 a4 = *reinterpret_cast<const float4*>(&sA[k][ty * 4]);
        float4 w4 = *reinterpret_cast<const float4*>(&sW[k][tx * 4]);
        float av[4] = {a4.x, a4.y, a4.z, a4.w};
        float wv[4] = {w4.x, w4.y, w4.z, w4.w};
        #pragma unroll
        for (int r = 0; r < 4; ++r)
            #pragma unroll
            for (int c = 0; c < 4; ++c)
                acc[r][c] = fmaf(av[r], wv[c], acc[r][c]);
    }
    #pragma unroll
    for (int r = 0; r < 4; ++r) {
        int row = r0 + ty * 4 + r;
        if (row < n) {
            float di = dinv[row];
            float4 o = {acc[r][0] * di, acc[r][1] * di, acc[r][2] * di, acc[r][3] * di};
            *reinterpret_cast<float4*>(hs2 + (size_t)row * 64 + tx * 4) = o;
        }
    }
}

// out[i,:] = relu((hs2[i,:] + sum_{s} hs2[s,:]) * dinv[i] + b2), 16 lanes/node
__global__ __launch_bounds__(256) void k_agg2(const int* __restrict__ rowptr,
                                              const int* __restrict__ eidx,
                                              const float* __restrict__ hs,
                                              const float* __restrict__ dinv,
                                              const float* __restrict__ b2,
                                              float* __restrict__ out, int n) {
    int t = blockIdx.x * blockDim.x + threadIdx.x;
    int node = t >> 4;
    if (node >= n) return;
    int lane = t & 15;
    const size_t co = (size_t)lane * 4;
    int b = rowptr[node], eN = rowptr[node + 1];
    float4 a = *reinterpret_cast<const float4*>(hs + (size_t)node * 64 + co);
    int e = b;
    for (; e + 4 <= eN; e += 4) {
        int s0 = eidx[e], s1 = eidx[e + 1], s2 = eidx[e + 2], s3 = eidx[e + 3];
        float4 v0 = *reinterpret_cast<const float4*>(hs + (size_t)s0 * 64 + co);
        float4 v1 = *reinterpret_cast<const float4*>(hs + (size_t)s1 * 64 + co);
        float4 v2 = *reinterpret_cast<const float4*>(hs + (size_t)s2 * 64 + co);
        float4 v3 = *reinterpret_cast<const float4*>(hs + (size_t)s3 * 64 + co);
        a.x += (v0.x + v1.x) + (v2.x + v3.x);
        a.y += (v0.y + v1.y) + (v2.y + v3.y);
        a.z += (v0.z + v1.z) + (v2.z + v3.z);
        a.w += (v0.w + v1.w) + (v2.w + v3.w);
    }
    for (; e < eN; ++e) {
        int s = eidx[e];
        float4 v = *reinterpret_cast<const float4*>(hs + (size_t)s * 64 + co);
        a.x += v.x; a.y += v.y; a.z += v.z; a.w += v.w;
    }
    float di = dinv[node];
    const float4 bb = *reinterpret_cast<const float4*>(b2 + co);
    float4 o;
    o.x = fmaxf(fmaf(a.x, di, bb.x), 0.f);
    o.y = fmaxf(fmaf(a.y, di, bb.y), 0.f);
    o.z = fmaxf(fmaf(a.z, di, bb.z), 0.f);
    o.w = fmaxf(fmaf(a.w, di, bb.w), 0.f);
    *reinterpret_cast<float4*>(out + (size_t)node * 64 + co) = o;
}

extern "C" void kernel_launch(void* const* d_in, const int* in_sizes, int n_in,
                              void* d_out, int out_size, void* d_ws, size_t ws_size,
                              hipStream_t stream) {
    const float* x  = (const float*)d_in[0];
    const int*   ei = (const int*)d_in[1];
    const float* W1 = (const float*)d_in[2];
    const float* b1 = (const float*)d_in[3];
    const float* W2 = (const float*)d_in[4];
    const float* b2 = (const float*)d_in[5];
    float* out = (float*)d_out;

    const int n = in_sizes[0] / 64;     // 50000
    const int E = in_sizes[1] / 2;      // 800000
    const int* src = ei;
    const int* dst = ei + E;

    char* ws = (char*)d_ws;
    size_t off = 0;
    auto alloc = [&](size_t bytes) { void* p = ws + off; off = (off + bytes + 255) & ~(size_t)255; return p; };
    const int G = divup(n, 256);
    int*   cnt    = (int*)  alloc((size_t)n * 4);
    int*   rowptr = (int*)  alloc((size_t)(n + 1) * 4);
    int*   cursor = (int*)  alloc((size_t)n * 4);
    float* dinv   = (float*)alloc((size_t)n * 4);
    int*   bsum   = (int*)  alloc((size_t)G * 4);
    int*   bbase  = (int*)  alloc((size_t)G * 4);
    int*   eidx   = (int*)  alloc((size_t)E * 4);
    float* hs1    = (float*)alloc((size_t)n * 128 * 4);
    float* h1f    = (float*)alloc((size_t)n * 128 * 4);
    float* hs2    = hs1;     // hs1 dead after k_agg1; reuse

    // CSR build
    hipMemsetAsync(cnt, 0, (size_t)n * 4, stream);
    k_count<<<divup(divup(E, 4), 256), 256, 0, stream>>>(dst, cnt, E);
    k_s1 <<<G, 256, 0, stream>>>(cnt, bsum, n);
    k_s2 <<<1, 256, 0, stream>>>(bsum, bbase, rowptr, G, n);
    k_s3 <<<G, 256, 0, stream>>>(cnt, bbase, rowptr, cursor, dinv, n);
    k_fill<<<divup(divup(E, 4), 256), 256, 0, stream>>>(src, dst, cursor, eidx, E);

    // layer 1
    k_gemm1<<<divup(n, 64), 256, 0, stream>>>(x, W1, dinv, hs1, n);
    k_agg1 <<<divup(n * 32, 256), 256, 0, stream>>>(rowptr, eidx, hs1, dinv, b1, h1f, n);

    // layer 2
    k_gemm2<<<divup(n, 64), 256, 0, stream>>>(h1f, W2, dinv, hs2, n);
    k_agg2 <<<divup(n * 16, 256), 256, 0, stream>>>(rowptr, eidx, hs2, dinv, b2, out, n);
}